// Round 5
// baseline (401.190 us; speedup 1.0000x reference)
//
#include <hip/hip_runtime.h>

typedef unsigned short u16;
typedef unsigned int u32;
typedef __bf16 bf16x8 __attribute__((ext_vector_type(8)));
typedef float floatx4 __attribute__((ext_vector_type(4)));
typedef int   intx4   __attribute__((ext_vector_type(4)));

#define EPS   1e-5f
#define LEAK  0.01f

// ---- conv tiling: block = 128 co x (4h x 32w) = 128 x 128 ----
#define IN_H   6
#define IN_W   34
#define NPOS   (IN_H * IN_W)       // 204 halo positions
#define CPAD   72                  // 64 ci + 8 pad -> 144B row, 16B aligned
#define CROW   132                 // f32 C-buffer row pad (mod4=0, bank shift 4)

#define XT_BYTES ((size_t)512 * 512 * 64 * 2)

__device__ __forceinline__ u16 f2bf(float f) {
    union { float f; u32 i; } v; v.f = f;
    u32 i = v.i;
    return (u16)((i + 0x7fffu + ((i >> 16) & 1u)) >> 16);   // RNE
}
__device__ __forceinline__ bf16x8 ld_frag(const u16* p) {
    uint4 d = *(const uint4*)p;
    return __builtin_bit_cast(bf16x8, d);
}

// ---------------------------------------------------------------------------
// x: [64][512][512] f32 (NCHW) -> xt: [512][512][64] bf16 (channels-last)
// ---------------------------------------------------------------------------
__global__ __launch_bounds__(256) void transpose_x(const float* __restrict__ x,
                                                   u16* __restrict__ xt)
{
    __shared__ u32 t[64][65];
    const int tid = threadIdx.x;
    const int s0  = blockIdx.x << 6;      // 64 consecutive spatial positions

    #pragma unroll
    for (int it = 0; it < 4; ++it) {
        int idx = it * 256 + tid;         // 1024 float4 loads: 64ci x 64w
        int ci = idx >> 4, wq = idx & 15;
        float4 d = *(const float4*)(x + (ci << 18) + s0 + (wq << 2));
        u32* row = &t[ci][wq << 2];
        row[0] = f2bf(d.x); row[1] = f2bf(d.y);
        row[2] = f2bf(d.z); row[3] = f2bf(d.w);
    }
    __syncthreads();
    #pragma unroll
    for (int it = 0; it < 2; ++it) {
        int idx = it * 256 + tid;         // 512 vec8 stores
        int sl = idx >> 3, cb = idx & 7;  // spatial-local, ci-block
        uint4 o;
        o.x = t[cb * 8 + 0][sl] | (t[cb * 8 + 1][sl] << 16);
        o.y = t[cb * 8 + 2][sl] | (t[cb * 8 + 3][sl] << 16);
        o.z = t[cb * 8 + 4][sl] | (t[cb * 8 + 5][sl] << 16);
        o.w = t[cb * 8 + 6][sl] | (t[cb * 8 + 7][sl] << 16);
        *(uint4*)(xt + ((s0 + sl) << 6) + (cb << 3)) = o;
    }
}

// ---------------------------------------------------------------------------
// W: [128 co][64 ci][3][3] f32 -> Wt: [18 kc][4 q][128 co][8 e] bf16
// (kc = r*2 + ci_half, r = kh*3+kw; ci = (kc&1)*32 + q*8 + e)
// Lane (q,l16) of conv reads its 16B A-fragment CONTIGUOUSLY:
//   addr = ((kc*4 + q)*128 + co)*8, lane stride 16B -> 4 x 256B segments/load
// ---------------------------------------------------------------------------
__global__ __launch_bounds__(256) void transpose_w(const float* __restrict__ w,
                                                   u16* __restrict__ wt)
{
    int idx = blockIdx.x * 256 + threadIdx.x;   // 73728 total = 18*4*128*8
    int e   = idx & 7;
    int co  = (idx >> 3) & 127;
    int qk  = idx >> 10;          // 0..71 = kc*4 + q
    int q   = qk & 3;
    int kc  = qk >> 2;            // 0..17
    int r   = kc >> 1;            // 0..8 = kh*3+kw
    int ci  = ((kc & 1) << 5) + (q << 3) + e;
    wt[idx] = f2bf(w[(co << 6 | ci) * 9 + r]);
}

// ---------------------------------------------------------------------------
// Implicit-GEMM conv + BN + LeakyReLU + mask. Block 256 thr (4 waves),
// tile 128co x 128n (4h x 32w). Wave (mi,ni): co [mi*64,+64), n [ni*64,+64).
// K = 576 = 18 kc of 32, as 3 bodies of 6 kc (kc = 6q + j, kh = q, kw = j>>1):
//   - all B ds_reads: ONE base VGPR + compile-time immediate offsets
//   - A-frags: 2-deep prefetch in 2 ROTATING buffers (af0/af1, 32 VGPR):
//     buf[j&1] consumed at kc, refilled for kc+2 right after its MFMAs ->
//     ~2 kc (>=400 cy) of L2-latency cover, vmcnt never drains to 0.
// Register budget: 64 AGPR acc + ~60 arch VGPR <= 128 total -> 4 waves/SIMD
// (R4 lesson: crossing 128 total drops to 2 waves/SIMD, -occupancy).
// Epilogue: C-tile through LDS (2 chunks 64co x 128n) -> float4/int4
// fully-coalesced mask+store.
// ---------------------------------------------------------------------------
__global__ __launch_bounds__(256, 4) void conv_mfma(
    const u16* __restrict__ xt,   const u16* __restrict__ wt,
    const float* __restrict__ gamma, const float* __restrict__ beta,
    const float* __restrict__ mean,  const float* __restrict__ var,
    const int* __restrict__ mask, float* __restrict__ out)
{
    __shared__ float s_scale[128];
    __shared__ float s_shift[128];
    // union: staging tile (29376 B) / C-buffer 64x132 f32 (33792 B)
    __shared__ __attribute__((aligned(16))) char smem[64 * CROW * 4];
    u16*   s_tile = (u16*)smem;
    float* cbuf   = (float*)smem;

    const int tid = threadIdx.x;
    const int bid = blockIdx.x;
    const int oh0 = (bid >> 4) << 2;    // 128 h-tiles of 4
    const int ow0 = (bid & 15) << 5;    // 16 w-tiles of 32

    if (tid < 128) {
        float sc = gamma[tid] * rsqrtf(var[tid] + EPS);
        s_scale[tid] = sc;
        s_shift[tid] = beta[tid] - mean[tid] * sc;
    }

    // stage 6x34 halo tile from channels-last bf16 xt (1632 b128 loads)
    #pragma unroll
    for (int it = 0; it < 7; ++it) {
        int idx = it * 256 + tid;
        if (idx < NPOS * 8) {
            int pos = idx >> 3, cb = idx & 7;
            int ihl = pos / IN_W;
            int iwl = pos - ihl * IN_W;
            int sh = oh0 - 1 + ihl; sh = sh < 0 ? -sh : (sh > 511 ? 1022 - sh : sh);
            int sw = ow0 - 1 + iwl; sw = sw < 0 ? -sw : (sw > 511 ? 1022 - sw : sw);
            uint4 d = *(const uint4*)(xt + (((sh << 9) + sw) << 6) + (cb << 3));
            *(uint4*)(s_tile + pos * CPAD + (cb << 3)) = d;
        }
    }
    __syncthreads();

    const int wave = tid >> 6;
    const int lane = tid & 63;
    const int quad = lane >> 4;
    const int l16  = lane & 15;
    const int mi   = wave >> 1;     // co 64-block
    const int ni   = wave & 1;      // n  64-block

    floatx4 acc[4][4];
    #pragma unroll
    for (int i = 0; i < 4; ++i)
        #pragma unroll
        for (int j = 0; j < 4; ++j)
            acc[i][j] = (floatx4){0.f, 0.f, 0.f, 0.f};

    // Single B-base; every ds_read offset is compile-time:
    //   off(ns,j,q) = vq + (ns>>1)*2448 + (ns&1)*1152 + (j>>1)*72 + (j&1)*32
    // (2448 = IN_W*CPAD, 1152 = 16*CPAD; vq advances 2448/body since kh=q)
    u16* vq = s_tile + ni * 2 * IN_W * CPAD + l16 * CPAD + quad * 8;
#define BOFFS(ns, j) (((ns) >> 1) * 2448 + ((ns) & 1) * 1152 + ((j) >> 1) * CPAD + ((j) & 1) * 32)

    // A-fragment global base: Wt[((kc*4 + q)*128 + mi*64 + cs*16 + l16)*8]
    // lane stride = 8 u16 = 16B -> coalesced 256B segments
    const u16* abase = wt + (quad << 10) + (mi << 9) + (l16 << 3);
    const u16* aptr  = abase;        // tracks kc = 6q

    bf16x8 af0[4], af1[4];
    #pragma unroll
    for (int cs = 0; cs < 4; ++cs) af0[cs] = ld_frag(abase + (cs << 7));
    #pragma unroll
    for (int cs = 0; cs < 4; ++cs) af1[cs] = ld_frag(abase + (1 << 12) + (cs << 7));

    // one kc step: B ds_reads (imm offsets) -> 16 MFMA -> refill BUF <- kc+2
#define KJ(BUF, J, DOREF)                                                    \
    {                                                                        \
        bf16x8 bfr[4];                                                       \
        bfr[0] = ld_frag(vq + BOFFS(0, J));                                  \
        bfr[1] = ld_frag(vq + BOFFS(1, J));                                  \
        bfr[2] = ld_frag(vq + BOFFS(2, J));                                  \
        bfr[3] = ld_frag(vq + BOFFS(3, J));                                  \
        _Pragma("unroll")                                                    \
        for (int cs = 0; cs < 4; ++cs)                                       \
            _Pragma("unroll")                                                \
            for (int ns = 0; ns < 4; ++ns)                                   \
                acc[cs][ns] = __builtin_amdgcn_mfma_f32_16x16x32_bf16(       \
                    BUF[cs], bfr[ns], acc[cs][ns], 0, 0, 0);                 \
        if (DOREF) {                                                         \
            _Pragma("unroll")                                                \
            for (int cs = 0; cs < 4; ++cs)                                   \
                BUF[cs] = ld_frag(aptr + (((J) + 2) << 12) + (cs << 7));     \
        }                                                                    \
    }

    #pragma unroll 1
    for (int q = 0; q < 2; ++q) {
        KJ(af0, 0, 1) KJ(af1, 1, 1) KJ(af0, 2, 1)
        KJ(af1, 3, 1) KJ(af0, 4, 1) KJ(af1, 5, 1)
        vq   += IN_W * CPAD;         // kh += 1
        aptr += 6 << 12;             // kc += 6
    }
    // last body (q = 2): refill only while kc+2 <= 17 (j <= 3)
    KJ(af0, 0, 1) KJ(af1, 1, 1) KJ(af0, 2, 1)
    KJ(af1, 3, 1) KJ(af0, 4, 0) KJ(af1, 5, 0)
#undef KJ
#undef BOFFS

    __syncthreads();   // all LDS B-reads done; cbuf may overwrite s_tile

    // ---- epilogue: 2 chunks of 64co x 128n through LDS ----
    // write: row = mi*32 + j*16 + quad*4 + reg, col n = ni*64 + ns*16 + l16
    // read:  idx -> row = idx>>5, v = idx&31 (float4 col), co = (row>>5)*64
    //        + c*32 + (row&31); n = 4v -> h = v>>3, w4 = (v&7)*4
    #pragma unroll
    for (int c = 0; c < 2; ++c) {
        #pragma unroll
        for (int j = 0; j < 2; ++j) {
            const int cs  = c * 2 + j;
            const int row = mi * 32 + j * 16 + quad * 4;
            #pragma unroll
            for (int ns = 0; ns < 4; ++ns) {
                const int n = ni * 64 + ns * 16 + l16;
                float* p = cbuf + row * CROW + n;
                #pragma unroll
                for (int reg = 0; reg < 4; ++reg)
                    p[reg * CROW] = acc[cs][ns][reg];
            }
        }
        __syncthreads();
        #pragma unroll
        for (int k = 0; k < 8; ++k) {
            const int idx = k * 256 + tid;
            const int row = idx >> 5;
            const int v   = idx & 31;
            floatx4 y4 = *(const floatx4*)(cbuf + row * CROW + (v << 2));
            const int co = ((row >> 5) << 6) + (c << 5) + (row & 31);
            const float sc = s_scale[co], sh = s_shift[co];
            const int gidx = (co << 18) + ((oh0 + (v >> 3)) << 9) + ow0 + ((v & 7) << 2);
            intx4 m = __builtin_nontemporal_load((const intx4*)(mask + gidx));
            floatx4 o;
            float t0 = y4.x * sc + sh; o.x = m.x ? fmaxf(t0, t0 * LEAK) : 0.f;
            float t1 = y4.y * sc + sh; o.y = m.y ? fmaxf(t1, t1 * LEAK) : 0.f;
            float t2 = y4.z * sc + sh; o.z = m.z ? fmaxf(t2, t2 * LEAK) : 0.f;
            float t3 = y4.w * sc + sh; o.w = m.w ? fmaxf(t3, t3 * LEAK) : 0.f;
            __builtin_nontemporal_store(o, (floatx4*)(out + gidx));
        }
        if (c == 0) __syncthreads();
    }
}

extern "C" void kernel_launch(void* const* d_in, const int* in_sizes, int n_in,
                              void* d_out, int out_size, void* d_ws, size_t ws_size,
                              hipStream_t stream)
{
    (void)in_sizes; (void)n_in; (void)out_size; (void)ws_size;
    const float* x     = (const float*)d_in[0];
    const float* W     = (const float*)d_in[1];
    const float* gamma = (const float*)d_in[2];
    const float* beta  = (const float*)d_in[3];
    const float* mean  = (const float*)d_in[4];
    const float* var   = (const float*)d_in[5];
    const int*   mask  = (const int*)d_in[6];
    float* out = (float*)d_out;

    u16* xt = (u16*)d_ws;
    u16* wt = (u16*)((char*)d_ws + XT_BYTES);

    transpose_w<<<288, 256, 0, stream>>>(W, wt);
    transpose_x<<<4096, 256, 0, stream>>>(x, xt);
    conv_mfma<<<2048, 256, 0, stream>>>(xt, wt, gamma, beta, mean, var, mask, out);
}

// Round 6
// 323.183 us; speedup vs baseline: 1.2414x; 1.2414x over previous
//
#include <hip/hip_runtime.h>

typedef unsigned short u16;
typedef unsigned int u32;
typedef __bf16 bf16x8 __attribute__((ext_vector_type(8)));
typedef float floatx4 __attribute__((ext_vector_type(4)));
typedef int   intx4   __attribute__((ext_vector_type(4)));

#define EPS   1e-5f
#define LEAK  0.01f

// ---- conv tiling: block = 128 co x (4h x 32w) = 128 x 128 ----
#define IN_H   6
#define IN_W   34
#define NPOS   (IN_H * IN_W)       // 204 halo positions
#define CPAD   72                  // 64 ci + 8 pad -> 144B row, 16B aligned
#define CROW   132                 // f32 C-buffer row pad (mod4=0, bank shift 4)

#define XT_BYTES ((size_t)512 * 512 * 64 * 2)

// LDS map (bytes): [0,29376) B-halo tile | [29376,37568) A buf0 | [37568,45760) A buf1
// cbuf (33792) unions [0,33792) -- A0 partially, dead by then.
#define A0_BYTE  29376
#define A_BUF_B  8192

__device__ __forceinline__ u16 f2bf(float f) {
    union { float f; u32 i; } v; v.f = f;
    u32 i = v.i;
    return (u16)((i + 0x7fffu + ((i >> 16) & 1u)) >> 16);   // RNE
}
__device__ __forceinline__ bf16x8 ld_frag(const u16* p) {
    uint4 d = *(const uint4*)p;
    return __builtin_bit_cast(bf16x8, d);
}

typedef __attribute__((address_space(3))) u32 lds_u32;
typedef const __attribute__((address_space(1))) u32 glb_u32;
#define GLL(gp, lp) __builtin_amdgcn_global_load_lds((glb_u32*)(gp), (lds_u32*)(lp), 16, 0, 0)

// ---------------------------------------------------------------------------
// x: [64][512][512] f32 (NCHW) -> xt: [512][512][64] bf16 (channels-last)
// ---------------------------------------------------------------------------
__global__ __launch_bounds__(256) void transpose_x(const float* __restrict__ x,
                                                   u16* __restrict__ xt)
{
    __shared__ u32 t[64][65];
    const int tid = threadIdx.x;
    const int s0  = blockIdx.x << 6;      // 64 consecutive spatial positions

    #pragma unroll
    for (int it = 0; it < 4; ++it) {
        int idx = it * 256 + tid;         // 1024 float4 loads: 64ci x 64w
        int ci = idx >> 4, wq = idx & 15;
        float4 d = *(const float4*)(x + (ci << 18) + s0 + (wq << 2));
        u32* row = &t[ci][wq << 2];
        row[0] = f2bf(d.x); row[1] = f2bf(d.y);
        row[2] = f2bf(d.z); row[3] = f2bf(d.w);
    }
    __syncthreads();
    #pragma unroll
    for (int it = 0; it < 2; ++it) {
        int idx = it * 256 + tid;         // 512 vec8 stores
        int sl = idx >> 3, cb = idx & 7;  // spatial-local, ci-block
        uint4 o;
        o.x = t[cb * 8 + 0][sl] | (t[cb * 8 + 1][sl] << 16);
        o.y = t[cb * 8 + 2][sl] | (t[cb * 8 + 3][sl] << 16);
        o.z = t[cb * 8 + 4][sl] | (t[cb * 8 + 5][sl] << 16);
        o.w = t[cb * 8 + 6][sl] | (t[cb * 8 + 7][sl] << 16);
        *(uint4*)(xt + ((s0 + sl) << 6) + (cb << 3)) = o;
    }
}

// ---------------------------------------------------------------------------
// W: [128 co][64 ci][3][3] f32 -> Wt: [18 kc][4 q][128 co][8 e] bf16
// (kc = r*2 + ci_half, r = kh*3+kw; ci = (kc&1)*32 + q*8 + e)
// One kc slab = 8192 B, loaded linearly to LDS by global_load_lds.
// ---------------------------------------------------------------------------
__global__ __launch_bounds__(256) void transpose_w(const float* __restrict__ w,
                                                   u16* __restrict__ wt)
{
    int idx = blockIdx.x * 256 + threadIdx.x;   // 73728 total = 18*4*128*8
    int e   = idx & 7;
    int co  = (idx >> 3) & 127;
    int qk  = idx >> 10;          // 0..71 = kc*4 + q
    int q   = qk & 3;
    int kc  = qk >> 2;            // 0..17
    int r   = kc >> 1;            // 0..8 = kh*3+kw
    int ci  = ((kc & 1) << 5) + (q << 3) + e;
    wt[idx] = f2bf(w[(co << 6 | ci) * 9 + r]);
}

// ---------------------------------------------------------------------------
// Implicit-GEMM conv + BN + LeakyReLU + mask. Block 256 thr (4 waves),
// tile 128co x 128n (4h x 32w). Wave (mi,ni): co [mi*64,+64), n [ni*64,+64).
// K = 576 = 18 kc of 32. A (weights) double-buffered in LDS via async
// global_load_lds (zero register cost -- R4/R5 lesson: register prefetch
// deeper than 1 kc cannot fit 128-reg budget at 4 waves/SIMD).
// Per kc: issue 2 GLL for kc+1 -> 4 A ds_reads + 4 B ds_reads (all imm
// offsets, loop fully unrolled; barriers fence hoisting so no R3-style
// spill) -> 16 MFMA -> barrier (vmcnt drain = slab ready + buffer free).
// Epilogue: C-tile through LDS (2 chunks 64co x 128n) -> float4/int4
// fully-coalesced mask+store.
// ---------------------------------------------------------------------------
__global__ __launch_bounds__(256, 4) void conv_mfma(
    const u16* __restrict__ xt,   const u16* __restrict__ wt,
    const float* __restrict__ gamma, const float* __restrict__ beta,
    const float* __restrict__ mean,  const float* __restrict__ var,
    const int* __restrict__ mask, float* __restrict__ out)
{
    __shared__ float s_scale[128];
    __shared__ float s_shift[128];
    __shared__ __attribute__((aligned(16))) char smem[A0_BYTE + 2 * A_BUF_B];
    u16*   s_tile = (u16*)smem;
    u16*   s_a    = (u16*)(smem + A0_BYTE);
    float* cbuf   = (float*)smem;

    const int tid = threadIdx.x;
    const int bid = blockIdx.x;
    const int oh0 = (bid >> 4) << 2;    // 128 h-tiles of 4
    const int ow0 = (bid & 15) << 5;    // 16 w-tiles of 32

    const int wave = tid >> 6;
    const int lane = tid & 63;
    const int quad = lane >> 4;
    const int l16  = lane & 15;
    const int mi   = wave >> 1;     // co 64-block
    const int ni   = wave & 1;      // n  64-block

    // ---- A-stage addressing: slab kc at wt+kc*8192B, linear to LDS ----
    // issue i (0,1), wave w: bytes [(i*4+w)*1024, +1024), lane gives +lane*16
    const char* g0 = (const char*)wt + (wave << 10) + (lane << 4);
    const char* g1 = g0 + 4096;
    u16* ld0 = s_a + (wave << 9);          // + wave*1024 B (u16 units)
    u16* ld1 = ld0 + 2048;                 // + 4096 B

    // prologue: kc=0 slab into buf0 (drained by the post-staging barrier)
    GLL(g0, ld0);
    GLL(g1, ld1);
    g0 += A_BUF_B; g1 += A_BUF_B;

    if (tid < 128) {
        float sc = gamma[tid] * rsqrtf(var[tid] + EPS);
        s_scale[tid] = sc;
        s_shift[tid] = beta[tid] - mean[tid] * sc;
    }

    // stage 6x34 halo tile from channels-last bf16 xt (1632 b128 loads)
    #pragma unroll
    for (int it = 0; it < 7; ++it) {
        int idx = it * 256 + tid;
        if (idx < NPOS * 8) {
            int pos = idx >> 3, cb = idx & 7;
            int ihl = pos / IN_W;
            int iwl = pos - ihl * IN_W;
            int sh = oh0 - 1 + ihl; sh = sh < 0 ? -sh : (sh > 511 ? 1022 - sh : sh);
            int sw = ow0 - 1 + iwl; sw = sw < 0 ? -sw : (sw > 511 ? 1022 - sw : sw);
            uint4 d = *(const uint4*)(xt + (((sh << 9) + sw) << 6) + (cb << 3));
            *(uint4*)(s_tile + pos * CPAD + (cb << 3)) = d;
        }
    }
    __syncthreads();   // halo staged AND A-slab kc=0 landed (vmcnt drained)

    floatx4 acc[4][4];
    #pragma unroll
    for (int i = 0; i < 4; ++i)
        #pragma unroll
        for (int j = 0; j < 4; ++j)
            acc[i][j] = (floatx4){0.f, 0.f, 0.f, 0.f};

    // B ds_read base (u16): n = ni*64 + ns*16 + l16, h=n>>5, w=n&31
    u16* vq = s_tile + (ni * 2 * IN_W + l16) * CPAD + quad * 8;
    // imm offset per (ns, kc): kh=(kc>>1)/3, kw=(kc>>1)%3
#define BOFF(ns, KC) ((((ns) >> 1) + ((KC) >> 1) / 3) * IN_W * CPAD + \
                      ((ns) & 1) * 16 * CPAD + (((KC) >> 1) % 3) * CPAD + ((KC) & 1) * 32)

    // A ds_read base (u16): buf + quad*2048B + mi*1024B + l16*16B, cs at +256B
    u16* a_rd = s_a + (quad << 10) + (mi << 9) + (l16 << 3);

#define KBODY(KC)                                                            \
    {                                                                        \
        if ((KC) < 17) {                                                     \
            GLL(g0, ld0 + ((((KC) + 1) & 1) << 12));                         \
            GLL(g1, ld1 + ((((KC) + 1) & 1) << 12));                         \
            g0 += A_BUF_B; g1 += A_BUF_B;                                    \
        }                                                                    \
        const int AB = ((KC) & 1) << 12;   /* u16: buffer toggle (8192 B) */ \
        bf16x8 afr[4], bfr[4];                                               \
        afr[0] = ld_frag(a_rd + AB);                                         \
        afr[1] = ld_frag(a_rd + AB + 128);                                   \
        afr[2] = ld_frag(a_rd + AB + 256);                                   \
        afr[3] = ld_frag(a_rd + AB + 384);                                   \
        bfr[0] = ld_frag(vq + BOFF(0, KC));                                  \
        bfr[1] = ld_frag(vq + BOFF(1, KC));                                  \
        bfr[2] = ld_frag(vq + BOFF(2, KC));                                  \
        bfr[3] = ld_frag(vq + BOFF(3, KC));                                  \
        _Pragma("unroll")                                                    \
        for (int cs = 0; cs < 4; ++cs)                                       \
            _Pragma("unroll")                                                \
            for (int ns = 0; ns < 4; ++ns)                                   \
                acc[cs][ns] = __builtin_amdgcn_mfma_f32_16x16x32_bf16(       \
                    afr[cs], bfr[ns], acc[cs][ns], 0, 0, 0);                 \
        __syncthreads();                                                     \
    }

    KBODY(0)  KBODY(1)  KBODY(2)  KBODY(3)  KBODY(4)  KBODY(5)
    KBODY(6)  KBODY(7)  KBODY(8)  KBODY(9)  KBODY(10) KBODY(11)
    KBODY(12) KBODY(13) KBODY(14) KBODY(15) KBODY(16) KBODY(17)
#undef KBODY
#undef BOFF

    // (final KBODY barrier = pre-epilogue barrier; cbuf overlap is safe)

    // ---- epilogue: 2 chunks of 64co x 128n through LDS ----
    // write: row = mi*32 + j*16 + quad*4 + reg, col n = ni*64 + ns*16 + l16
    // read:  idx -> row = idx>>5, v = idx&31 (float4 col), co = (row>>5)*64
    //        + c*32 + (row&31); n = 4v -> h = v>>3, w4 = (v&7)*4
    #pragma unroll
    for (int c = 0; c < 2; ++c) {
        #pragma unroll
        for (int j = 0; j < 2; ++j) {
            const int cs  = c * 2 + j;
            const int row = mi * 32 + j * 16 + quad * 4;
            #pragma unroll
            for (int ns = 0; ns < 4; ++ns) {
                const int n = ni * 64 + ns * 16 + l16;
                float* p = cbuf + row * CROW + n;
                #pragma unroll
                for (int reg = 0; reg < 4; ++reg)
                    p[reg * CROW] = acc[cs][ns][reg];
            }
        }
        __syncthreads();
        #pragma unroll
        for (int k = 0; k < 8; ++k) {
            const int idx = k * 256 + tid;
            const int row = idx >> 5;
            const int v   = idx & 31;
            floatx4 y4 = *(const floatx4*)(cbuf + row * CROW + (v << 2));
            const int co = ((row >> 5) << 6) + (c << 5) + (row & 31);
            const float sc = s_scale[co], sh = s_shift[co];
            const int gidx = (co << 18) + ((oh0 + (v >> 3)) << 9) + ow0 + ((v & 7) << 2);
            intx4 m = __builtin_nontemporal_load((const intx4*)(mask + gidx));
            floatx4 o;
            float t0 = y4.x * sc + sh; o.x = m.x ? fmaxf(t0, t0 * LEAK) : 0.f;
            float t1 = y4.y * sc + sh; o.y = m.y ? fmaxf(t1, t1 * LEAK) : 0.f;
            float t2 = y4.z * sc + sh; o.z = m.z ? fmaxf(t2, t2 * LEAK) : 0.f;
            float t3 = y4.w * sc + sh; o.w = m.w ? fmaxf(t3, t3 * LEAK) : 0.f;
            __builtin_nontemporal_store(o, (floatx4*)(out + gidx));
        }
        if (c == 0) __syncthreads();
    }
}

extern "C" void kernel_launch(void* const* d_in, const int* in_sizes, int n_in,
                              void* d_out, int out_size, void* d_ws, size_t ws_size,
                              hipStream_t stream)
{
    (void)in_sizes; (void)n_in; (void)out_size; (void)ws_size;
    const float* x     = (const float*)d_in[0];
    const float* W     = (const float*)d_in[1];
    const float* gamma = (const float*)d_in[2];
    const float* beta  = (const float*)d_in[3];
    const float* mean  = (const float*)d_in[4];
    const float* var   = (const float*)d_in[5];
    const int*   mask  = (const int*)d_in[6];
    float* out = (float*)d_out;

    u16* xt = (u16*)d_ws;
    u16* wt = (u16*)((char*)d_ws + XT_BYTES);

    transpose_w<<<288, 256, 0, stream>>>(W, wt);
    transpose_x<<<4096, 256, 0, stream>>>(x, xt);
    conv_mfma<<<2048, 256, 0, stream>>>(xt, wt, gamma, beta, mean, var, mask, out);
}

// Round 7
// 323.051 us; speedup vs baseline: 1.2419x; 1.0004x over previous
//
#include <hip/hip_runtime.h>

typedef unsigned short u16;
typedef unsigned int u32;
typedef __bf16 bf16x8 __attribute__((ext_vector_type(8)));
typedef float floatx4 __attribute__((ext_vector_type(4)));
typedef int   intx4   __attribute__((ext_vector_type(4)));

#define EPS   1e-5f
#define LEAK  0.01f

// ---- conv tiling: block = 128 co x (4h x 32w) = 128 x 128 ----
#define IN_H   6
#define IN_W   34
#define NPOS   (IN_H * IN_W)       // 204 halo positions
#define CPAD   72                  // 64 ci + 8 pad -> 144B row, 16B aligned
#define CROW   132                 // f32 C-buffer row pad (mod4=0, bank shift 4)

__device__ __forceinline__ u16 f2bf(float f) {
    union { float f; u32 i; } v; v.f = f;
    u32 i = v.i;
    return (u16)((i + 0x7fffu + ((i >> 16) & 1u)) >> 16);   // RNE
}
__device__ __forceinline__ bf16x8 ld_frag(const u16* p) {
    uint4 d = *(const uint4*)p;
    return __builtin_bit_cast(bf16x8, d);
}

// ---------------------------------------------------------------------------
// W: [128 co][64 ci][3][3] f32 -> Wt: [18 kc][4 q][128 co][8 e] bf16
// (kc = r*2 + ci_half, r = kh*3+kw; ci = (kc&1)*32 + q*8 + e)
// Lane (q,l16) of conv reads its 16B A-fragment CONTIGUOUSLY:
//   addr = ((kc*4 + q)*128 + co)*8, lane stride 16B -> 4 x 256B segments/load
// ---------------------------------------------------------------------------
__global__ __launch_bounds__(256) void transpose_w(const float* __restrict__ w,
                                                   u16* __restrict__ wt)
{
    int idx = blockIdx.x * 256 + threadIdx.x;   // 73728 total = 18*4*128*8
    int e   = idx & 7;
    int co  = (idx >> 3) & 127;
    int qk  = idx >> 10;          // 0..71 = kc*4 + q
    int q   = qk & 3;
    int kc  = qk >> 2;            // 0..17
    int r   = kc >> 1;            // 0..8 = kh*3+kw
    int ci  = ((kc & 1) << 5) + (q << 3) + e;
    wt[idx] = f2bf(w[(co << 6 | ci) * 9 + r]);
}

// ---------------------------------------------------------------------------
// FUSED implicit-GEMM conv + BN + LeakyReLU + mask, reading x DIRECTLY
// (NCHW f32 -> bf16 halo tile staged in-kernel; the former transpose_x
// pass and its 96 MB of traffic + launch gap are eliminated).
// Block 256 thr (4 waves), tile 128co x 128n (4h x 32w).
// Staging: 384 (ci,ihl) rows x 40 aligned floats (2 half-rows of 5 float4
// per unit, 768 units, 3/thread, ci-major), f2bf inline, ds_write_b16 into
// s_tile[pos][ci] (layout unchanged). Reflect: span-clamp + 2 fixups.
// Main loop + epilogue: verbatim R2 optimum (1-deep A-prefetch from
// fragment-contiguous Wt, 4 waves/SIMD, K=18x32, LDS C-epilogue).
// ---------------------------------------------------------------------------
__global__ __launch_bounds__(256, 4) void conv_mfma(
    const float* __restrict__ x,  const u16* __restrict__ wt,
    const float* __restrict__ gamma, const float* __restrict__ beta,
    const float* __restrict__ mean,  const float* __restrict__ var,
    const int* __restrict__ mask, float* __restrict__ out)
{
    __shared__ float s_scale[128];
    __shared__ float s_shift[128];
    // union: staging tile (29376 B) / C-buffer 64x132 f32 (33792 B)
    __shared__ __attribute__((aligned(16))) char smem[64 * CROW * 4];
    u16*   s_tile = (u16*)smem;
    float* cbuf   = (float*)smem;

    const int tid = threadIdx.x;
    const int bid = blockIdx.x;
    const int oh0 = (bid >> 4) << 2;    // 128 h-tiles of 4
    const int ow0 = (bid & 15) << 5;    // 16 w-tiles of 32

    if (tid < 128) {
        float sc = gamma[tid] * rsqrtf(var[tid] + EPS);
        s_scale[tid] = sc;
        s_shift[tid] = beta[tid] - mean[tid] * sc;
    }

    // ---- stage 6x34 halo tile DIRECTLY from x (NCHW f32) ----
    // rows: row = ci*6 + ihl (ci-major for 2KB-stride locality)
    // unit = it*256+tid (768): row = unit>>1, half = unit&1; 5 float4/unit
    // w-span [wb, wb+40) with wb clamped so all loads are in-bounds.
    const int wb = (ow0 == 0) ? 0 : ((ow0 == 480) ? 472 : ow0 - 4);
    #pragma unroll
    for (int it = 0; it < 3; ++it) {
        int unit = it * 256 + tid;
        int row  = unit >> 1;
        int half = unit & 1;
        int ci   = row / 6;
        int ihl  = row - ci * 6;
        int sh = oh0 - 1 + ihl; sh = sh < 0 ? -sh : (sh > 511 ? 1022 - sh : sh);
        const int w0 = wb + half * 20;
        const float* src = x + (ci << 18) + (sh << 9) + w0;
        #pragma unroll
        for (int k = 0; k < 5; ++k) {
            float4 d = *(const float4*)(src + (k << 2));
            #pragma unroll
            for (int j = 0; j < 4; ++j) {
                float f = (j == 0) ? d.x : (j == 1) ? d.y : (j == 2) ? d.z : d.w;
                const int w  = w0 + (k << 2) + j;
                const int wl = w - ow0 + 1;
                const u16 b = f2bf(f);
                if (wl >= 0 && wl < IN_W)
                    s_tile[(ihl * IN_W + wl) * CPAD + ci] = b;
                if (ow0 == 0 && w == 1)                 // reflect w=-1 -> 1
                    s_tile[(ihl * IN_W + 0) * CPAD + ci] = b;
                if (ow0 == 480 && w == 510)             // reflect w=512 -> 510
                    s_tile[(ihl * IN_W + 33) * CPAD + ci] = b;
            }
        }
    }
    __syncthreads();

    const int wave = tid >> 6;
    const int lane = tid & 63;
    const int quad = lane >> 4;
    const int l16  = lane & 15;
    const int mi   = wave >> 1;     // co 64-block
    const int ni   = wave & 1;      // n  64-block

    floatx4 acc[4][4];
    #pragma unroll
    for (int i = 0; i < 4; ++i)
        #pragma unroll
        for (int j = 0; j < 4; ++j)
            acc[i][j] = (floatx4){0.f, 0.f, 0.f, 0.f};

    // B-fragment LDS base per n-subtile (at kh=kw=0, ci = quad*8)
    int bbase[4];
    #pragma unroll
    for (int ns = 0; ns < 4; ++ns) {
        int n = ni * 64 + ns * 16 + l16;                 // n = h*32 + w
        bbase[ns] = ((n >> 5) * IN_W + (n & 31)) * CPAD + quad * 8;
    }
    // A-fragment global base: Wt[((kc*4 + q)*128 + mi*64 + cs*16 + l16)*8]
    // lane stride = 8 u16 = 16B -> coalesced 256B segments
    const u16* abase = wt + (quad << 10) + (mi << 9) + (l16 << 3);

    bf16x8 af_next[4];
    #pragma unroll
    for (int cs = 0; cs < 4; ++cs)
        af_next[cs] = ld_frag(abase + (cs << 7));

    #pragma unroll 1
    for (int kc = 0; kc < 18; ++kc) {
        const int r    = kc >> 1;
        const int kh   = r / 3;
        const int kw   = r - kh * 3;
        const int cib  = (kc & 1) << 5;
        const int boff = (kh * IN_W + kw) * CPAD + cib;

        bf16x8 af[4];
        #pragma unroll
        for (int cs = 0; cs < 4; ++cs) af[cs] = af_next[cs];

        bf16x8 bfr[4];
        #pragma unroll
        for (int ns = 0; ns < 4; ++ns)
            bfr[ns] = ld_frag(s_tile + bbase[ns] + boff);

        if (kc < 17) {
            const int kc1 = kc + 1;
            #pragma unroll
            for (int cs = 0; cs < 4; ++cs)
                af_next[cs] = ld_frag(abase + (kc1 << 12) + (cs << 7));
        }

        #pragma unroll
        for (int cs = 0; cs < 4; ++cs)
            #pragma unroll
            for (int ns = 0; ns < 4; ++ns)
                acc[cs][ns] = __builtin_amdgcn_mfma_f32_16x16x32_bf16(
                    af[cs], bfr[ns], acc[cs][ns], 0, 0, 0);
    }

    __syncthreads();   // all LDS B-reads done; cbuf may overwrite s_tile

    // ---- epilogue: 2 chunks of 64co x 128n through LDS ----
    // write: row = mi*32 + j*16 + quad*4 + reg, col n = ni*64 + ns*16 + l16
    // read:  idx -> row = idx>>5, v = idx&31 (float4 col), co = (row>>5)*64
    //        + c*32 + (row&31); n = 4v -> h = v>>3, w4 = (v&7)*4
    #pragma unroll
    for (int c = 0; c < 2; ++c) {
        #pragma unroll
        for (int j = 0; j < 2; ++j) {
            const int cs  = c * 2 + j;
            const int row = mi * 32 + j * 16 + quad * 4;
            #pragma unroll
            for (int ns = 0; ns < 4; ++ns) {
                const int n = ni * 64 + ns * 16 + l16;
                float* p = cbuf + row * CROW + n;
                #pragma unroll
                for (int reg = 0; reg < 4; ++reg)
                    p[reg * CROW] = acc[cs][ns][reg];
            }
        }
        __syncthreads();
        #pragma unroll
        for (int k = 0; k < 8; ++k) {
            const int idx = k * 256 + tid;
            const int row = idx >> 5;
            const int v   = idx & 31;
            floatx4 y4 = *(const floatx4*)(cbuf + row * CROW + (v << 2));
            const int co = ((row >> 5) << 6) + (c << 5) + (row & 31);
            const float sc = s_scale[co], sh = s_shift[co];
            const int gidx = (co << 18) + ((oh0 + (v >> 3)) << 9) + ow0 + ((v & 7) << 2);
            intx4 m = __builtin_nontemporal_load((const intx4*)(mask + gidx));
            floatx4 o;
            float t0 = y4.x * sc + sh; o.x = m.x ? fmaxf(t0, t0 * LEAK) : 0.f;
            float t1 = y4.y * sc + sh; o.y = m.y ? fmaxf(t1, t1 * LEAK) : 0.f;
            float t2 = y4.z * sc + sh; o.z = m.z ? fmaxf(t2, t2 * LEAK) : 0.f;
            float t3 = y4.w * sc + sh; o.w = m.w ? fmaxf(t3, t3 * LEAK) : 0.f;
            __builtin_nontemporal_store(o, (floatx4*)(out + gidx));
        }
        if (c == 0) __syncthreads();
    }
}

extern "C" void kernel_launch(void* const* d_in, const int* in_sizes, int n_in,
                              void* d_out, int out_size, void* d_ws, size_t ws_size,
                              hipStream_t stream)
{
    (void)in_sizes; (void)n_in; (void)out_size; (void)ws_size;
    const float* x     = (const float*)d_in[0];
    const float* W     = (const float*)d_in[1];
    const float* gamma = (const float*)d_in[2];
    const float* beta  = (const float*)d_in[3];
    const float* mean  = (const float*)d_in[4];
    const float* var   = (const float*)d_in[5];
    const int*   mask  = (const int*)d_in[6];
    float* out = (float*)d_out;

    u16* wt = (u16*)d_ws;

    transpose_w<<<288, 256, 0, stream>>>(W, wt);
    conv_mfma<<<2048, 256, 0, stream>>>(x, wt, gamma, beta, mean, var, mask, out);
}

// Round 8
// 308.158 us; speedup vs baseline: 1.3019x; 1.0483x over previous
//
#include <hip/hip_runtime.h>

typedef unsigned short u16;
typedef unsigned int u32;
typedef __bf16 bf16x8 __attribute__((ext_vector_type(8)));
typedef __bf16 bf16x2 __attribute__((ext_vector_type(2)));
typedef float floatx4 __attribute__((ext_vector_type(4)));
typedef int   intx4   __attribute__((ext_vector_type(4)));

#define EPS   1e-5f
#define LEAK  0.01f

// ---- conv tiling: block = 128 co x (4h x 32w) = 128 x 128 ----
#define IN_H   6
#define IN_W   34
#define NPOS   (IN_H * IN_W)       // 204 halo positions
#define CPAD   72                  // 64 ci + 8 pad -> 144B row, 16B aligned
#define CROW   132                 // f32 C-buffer row pad (mod4=0, bank shift 4)

__device__ __forceinline__ u16 f2bf(float f) {
    union { float f; u32 i; } v; v.f = f;
    u32 i = v.i;
    return (u16)((i + 0x7fffu + ((i >> 16) & 1u)) >> 16);   // RNE
}
// pack 2 f32 -> 2 bf16 in a u32; compiler emits v_cvt_pk_bf16_f32 (RNE)
__device__ __forceinline__ u32 pkbf(float a, float b) {
    bf16x2 v = {(__bf16)a, (__bf16)b};
    return __builtin_bit_cast(u32, v);
}
__device__ __forceinline__ bf16x8 ld_frag(const u16* p) {
    uint4 d = *(const uint4*)p;
    return __builtin_bit_cast(bf16x8, d);
}

// ---------------------------------------------------------------------------
// W: [128 co][64 ci][3][3] f32 -> Wt: [18 kc][4 q][128 co][8 e] bf16
// (kc = r*2 + ci_half, r = kh*3+kw; ci = (kc&1)*32 + q*8 + e)
// Lane (q,l16) of conv reads its 16B A-fragment CONTIGUOUSLY:
//   addr = ((kc*4 + q)*128 + co)*8, lane stride 16B -> 4 x 256B segments/load
// ---------------------------------------------------------------------------
__global__ __launch_bounds__(256) void transpose_w(const float* __restrict__ w,
                                                   u16* __restrict__ wt)
{
    int idx = blockIdx.x * 256 + threadIdx.x;   // 73728 total = 18*4*128*8
    int e   = idx & 7;
    int co  = (idx >> 3) & 127;
    int qk  = idx >> 10;          // 0..71 = kc*4 + q
    int q   = qk & 3;
    int kc  = qk >> 2;            // 0..17
    int r   = kc >> 1;            // 0..8 = kh*3+kw
    int ci  = ((kc & 1) << 5) + (q << 3) + e;
    wt[idx] = f2bf(w[(co << 6 | ci) * 9 + r]);
}

// ---------------------------------------------------------------------------
// FUSED implicit-GEMM conv + BN + LeakyReLU + mask, reading x DIRECTLY.
// Staging (R8): units of (8 ci x 4 w) = 8 float4 loads -> in-register
// 8x4 transpose via v_cvt_pk_bf16_f32 pairs -> 4 ds_write_b128 into
// s_tile[pos][ci] (layout unchanged). 480 units, 2/thread. Reflect:
// span-clamp + 2 unit-level b128 fixups. (R7 lesson: 60 scalar guarded
// ds_write_b16 + manual-RNE VALU cost ~40 us of conv time.)
// Main loop + epilogue: verbatim R2 optimum (1-deep A-prefetch from
// fragment-contiguous Wt, 4 waves/SIMD, K=18x32, LDS C-epilogue).
// ---------------------------------------------------------------------------
__global__ __launch_bounds__(256, 4) void conv_mfma(
    const float* __restrict__ x,  const u16* __restrict__ wt,
    const float* __restrict__ gamma, const float* __restrict__ beta,
    const float* __restrict__ mean,  const float* __restrict__ var,
    const int* __restrict__ mask, float* __restrict__ out)
{
    __shared__ float s_scale[128];
    __shared__ float s_shift[128];
    // union: staging tile (29376 B) / C-buffer 64x132 f32 (33792 B)
    __shared__ __attribute__((aligned(16))) char smem[64 * CROW * 4];
    u16*   s_tile = (u16*)smem;
    float* cbuf   = (float*)smem;

    const int tid = threadIdx.x;
    const int bid = blockIdx.x;
    const int oh0 = (bid >> 4) << 2;    // 128 h-tiles of 4
    const int ow0 = (bid & 15) << 5;    // 16 w-tiles of 32

    if (tid < 128) {
        float sc = gamma[tid] * rsqrtf(var[tid] + EPS);
        s_scale[tid] = sc;
        s_shift[tid] = beta[tid] - mean[tid] * sc;
    }

    // ---- stage 6x34 halo tile DIRECTLY from x (NCHW f32) ----
    // unit = cig*60 + ihl*10 + wu  (480 units; wu fastest -> coalesced)
    // loads: 8 ci planes (cig*8 + 0..7) at (sh, w0=wb+wu*4), 16B each
    // w-span [wb, wb+40) clamped in-bounds; reflect via 2 fixup writes.
    const int wb = (ow0 == 0) ? 0 : ((ow0 == 480) ? 472 : ow0 - 4);
    #pragma unroll
    for (int it = 0; it < 2; ++it) {
        int unit = it * 256 + tid;
        if (unit < 480) {
            int cig = unit / 60;
            int rem = unit - cig * 60;
            int ihl = rem / 10;
            int wu  = rem - ihl * 10;
            int sh = oh0 - 1 + ihl; sh = sh < 0 ? -sh : (sh > 511 ? 1022 - sh : sh);
            const int w0 = wb + (wu << 2);
            const float* src = x + (cig << 21) + (sh << 9) + w0;
            u32 ow[4][4];                     // [w j][ci pair pp]
            #pragma unroll
            for (int pp = 0; pp < 4; ++pp) {
                float4 a = *(const float4*)(src + ((pp << 1) << 18));
                float4 b = *(const float4*)(src + (((pp << 1) + 1) << 18));
                ow[0][pp] = pkbf(a.x, b.x);
                ow[1][pp] = pkbf(a.y, b.y);
                ow[2][pp] = pkbf(a.z, b.z);
                ow[3][pp] = pkbf(a.w, b.w);
            }
            #pragma unroll
            for (int j = 0; j < 4; ++j) {
                const int w  = w0 + j;
                const int wl = w - ow0 + 1;
                uint4 val = {ow[j][0], ow[j][1], ow[j][2], ow[j][3]};
                if (wl >= 0 && wl < IN_W)
                    *(uint4*)(s_tile + (ihl * IN_W + wl) * CPAD + (cig << 3)) = val;
                if (ow0 == 0 && w == 1)       // reflect w=-1 -> 1
                    *(uint4*)(s_tile + (ihl * IN_W + 0) * CPAD + (cig << 3)) = val;
                if (ow0 == 480 && w == 510)   // reflect w=512 -> 510
                    *(uint4*)(s_tile + (ihl * IN_W + 33) * CPAD + (cig << 3)) = val;
            }
        }
    }
    __syncthreads();

    const int wave = tid >> 6;
    const int lane = tid & 63;
    const int quad = lane >> 4;
    const int l16  = lane & 15;
    const int mi   = wave >> 1;     // co 64-block
    const int ni   = wave & 1;      // n  64-block

    floatx4 acc[4][4];
    #pragma unroll
    for (int i = 0; i < 4; ++i)
        #pragma unroll
        for (int j = 0; j < 4; ++j)
            acc[i][j] = (floatx4){0.f, 0.f, 0.f, 0.f};

    // B-fragment LDS base per n-subtile (at kh=kw=0, ci = quad*8)
    int bbase[4];
    #pragma unroll
    for (int ns = 0; ns < 4; ++ns) {
        int n = ni * 64 + ns * 16 + l16;                 // n = h*32 + w
        bbase[ns] = ((n >> 5) * IN_W + (n & 31)) * CPAD + quad * 8;
    }
    // A-fragment global base: Wt[((kc*4 + q)*128 + mi*64 + cs*16 + l16)*8]
    // lane stride = 8 u16 = 16B -> coalesced 256B segments
    const u16* abase = wt + (quad << 10) + (mi << 9) + (l16 << 3);

    bf16x8 af_next[4];
    #pragma unroll
    for (int cs = 0; cs < 4; ++cs)
        af_next[cs] = ld_frag(abase + (cs << 7));

    #pragma unroll 1
    for (int kc = 0; kc < 18; ++kc) {
        const int r    = kc >> 1;
        const int kh   = r / 3;
        const int kw   = r - kh * 3;
        const int cib  = (kc & 1) << 5;
        const int boff = (kh * IN_W + kw) * CPAD + cib;

        bf16x8 af[4];
        #pragma unroll
        for (int cs = 0; cs < 4; ++cs) af[cs] = af_next[cs];

        bf16x8 bfr[4];
        #pragma unroll
        for (int ns = 0; ns < 4; ++ns)
            bfr[ns] = ld_frag(s_tile + bbase[ns] + boff);

        if (kc < 17) {
            const int kc1 = kc + 1;
            #pragma unroll
            for (int cs = 0; cs < 4; ++cs)
                af_next[cs] = ld_frag(abase + (kc1 << 12) + (cs << 7));
        }

        #pragma unroll
        for (int cs = 0; cs < 4; ++cs)
            #pragma unroll
            for (int ns = 0; ns < 4; ++ns)
                acc[cs][ns] = __builtin_amdgcn_mfma_f32_16x16x32_bf16(
                    af[cs], bfr[ns], acc[cs][ns], 0, 0, 0);
    }

    __syncthreads();   // all LDS B-reads done; cbuf may overwrite s_tile

    // ---- epilogue: 2 chunks of 64co x 128n through LDS ----
    // write: row = mi*32 + j*16 + quad*4 + reg, col n = ni*64 + ns*16 + l16
    // read:  idx -> row = idx>>5, v = idx&31 (float4 col), co = (row>>5)*64
    //        + c*32 + (row&31); n = 4v -> h = v>>3, w4 = (v&7)*4
    #pragma unroll
    for (int c = 0; c < 2; ++c) {
        #pragma unroll
        for (int j = 0; j < 2; ++j) {
            const int cs  = c * 2 + j;
            const int row = mi * 32 + j * 16 + quad * 4;
            #pragma unroll
            for (int ns = 0; ns < 4; ++ns) {
                const int n = ni * 64 + ns * 16 + l16;
                float* p = cbuf + row * CROW + n;
                #pragma unroll
                for (int reg = 0; reg < 4; ++reg)
                    p[reg * CROW] = acc[cs][ns][reg];
            }
        }
        __syncthreads();
        #pragma unroll
        for (int k = 0; k < 8; ++k) {
            const int idx = k * 256 + tid;
            const int row = idx >> 5;
            const int v   = idx & 31;
            floatx4 y4 = *(const floatx4*)(cbuf + row * CROW + (v << 2));
            const int co = ((row >> 5) << 6) + (c << 5) + (row & 31);
            const float sc = s_scale[co], sh = s_shift[co];
            const int gidx = (co << 18) + ((oh0 + (v >> 3)) << 9) + ow0 + ((v & 7) << 2);
            intx4 m = __builtin_nontemporal_load((const intx4*)(mask + gidx));
            floatx4 o;
            float t0 = y4.x * sc + sh; o.x = m.x ? fmaxf(t0, t0 * LEAK) : 0.f;
            float t1 = y4.y * sc + sh; o.y = m.y ? fmaxf(t1, t1 * LEAK) : 0.f;
            float t2 = y4.z * sc + sh; o.z = m.z ? fmaxf(t2, t2 * LEAK) : 0.f;
            float t3 = y4.w * sc + sh; o.w = m.w ? fmaxf(t3, t3 * LEAK) : 0.f;
            __builtin_nontemporal_store(o, (floatx4*)(out + gidx));
        }
        if (c == 0) __syncthreads();
    }
}

extern "C" void kernel_launch(void* const* d_in, const int* in_sizes, int n_in,
                              void* d_out, int out_size, void* d_ws, size_t ws_size,
                              hipStream_t stream)
{
    (void)in_sizes; (void)n_in; (void)out_size; (void)ws_size;
    const float* x     = (const float*)d_in[0];
    const float* W     = (const float*)d_in[1];
    const float* gamma = (const float*)d_in[2];
    const float* beta  = (const float*)d_in[3];
    const float* mean  = (const float*)d_in[4];
    const float* var   = (const float*)d_in[5];
    const int*   mask  = (const int*)d_in[6];
    float* out = (float*)d_out;

    u16* wt = (u16*)d_ws;

    transpose_w<<<288, 256, 0, stream>>>(W, wt);
    conv_mfma<<<2048, 256, 0, stream>>>(x, wt, gamma, beta, mean, var, mask, out);
}